// Round 24
// baseline (710.800 us; speedup 1.0000x reference)
//
#include <hip/hip_runtime.h>
#include <cstdint>
#include <cstddef>

// ---------------- problem constants ----------------
#define BB   16      // batch
#define HH   7
#define WW   7
#define AA   12
#define KAA  588     // H*W*A
#define NN   16464   // 28*KA tube proposals per batch
#define NPAD 32768   // padded segment per batch (16 chunks of 2048)
#define PRE  2000
#define POST 300
#define SS   16      // frames

// base anchors from generate_anchors(16), baked (exact halves, f32-exact)
__device__ __constant__ float BASE_ANC[12][4] = {
  {-15.f,  -4.f,  30.f,  19.f},
  {-38.f, -16.f,  53.f,  31.f},
  {-84.f, -40.f,  99.f,  55.f},
  {-176.f,-88.f, 191.f, 103.f},
  {-8.f,   -8.f,  23.f,  23.f},
  {-24.f, -24.f,  39.f,  39.f},
  {-56.f, -56.f,  71.f,  71.f},
  {-120.f,-120.f,135.f, 135.f},
  {-3.f,  -14.f,  18.f,  29.f},
  {-14.f, -36.f,  29.f,  51.f},
  {-36.f, -80.f,  51.f,  95.f},
  {-80.f, -168.f, 95.f, 183.f},
};

__device__ __forceinline__ void decode_idx(int idx, int& s, int& j, int& h, int& w, int& a) {
  int local;
  if (idx < 588)       { s = 0; local = idx; }
  else if (idx < 3528) { s = 1; local = idx - 588; }
  else if (idx < 8820) { s = 2; local = idx - 3528; }
  else                 { s = 3; local = idx - 8820; }
  j = local / KAA;
  int anc = local - j * KAA;
  h = anc / (WW * AA);
  int rem = anc - h * (WW * AA);
  w = rem / AA;
  a = rem - w * AA;
}

// ---------------- fused key-gen + per-chunk sort (top-2048 stage 1) ----------
__global__ __launch_bounds__(1024) void chunk_sort(const float* __restrict__ s16,
                                                   const float* __restrict__ s12,
                                                   const float* __restrict__ s8,
                                                   const float* __restrict__ s4,
                                                   uint64_t* __restrict__ keys,
                                                   float* __restrict__ scores) {
  __shared__ uint64_t sh[2048];
  int chunk = blockIdx.x;                 // 16 chunks per batch
  int b = chunk >> 4;
  int c = chunk & 15;
  int t = threadIdx.x;

  #pragma unroll
  for (int k = 0; k < 2; ++k) {
    int slot = c * 2048 + t + k * 1024;
    uint64_t key = ~0ull;
    if (slot < NN) {
      int s, j, h, w, a;
      decode_idx(slot, s, j, h, w, a);
      const float* sp; int T;
      if (s == 0)      { sp = s16; T = 1; }
      else if (s == 1) { sp = s12; T = 5; }
      else if (s == 2) { sp = s8;  T = 9; }
      else             { sp = s4;  T = 13; }
      float sc = sp[(((b * (2*AA) + AA + a) * T + j) * HH + h) * WW + w];
      scores[b * NN + slot] = sc;
      uint32_t u = __float_as_uint(sc);
      uint32_t mono = (u & 0x80000000u) ? ~u : (u | 0x80000000u);
      key = ((uint64_t)(~mono) << 32) | (uint32_t)slot;
    }
    sh[t + k * 1024] = key;
  }
  __syncthreads();

  for (int k = 2; k <= 2048; k <<= 1) {
    for (int j = k >> 1; j >= 1; j >>= 1) {
      int i = ((t & ~(j - 1)) << 1) | (t & (j - 1));
      int p = i | j;
      bool asc = ((i & k) == 0);          // standalone ascending sort
      uint64_t x = sh[i], y = sh[p];
      bool sw = asc ? (x > y) : (x < y);
      if (sw) { sh[i] = y; sh[p] = x; }
      __syncthreads();
    }
  }
  uint64_t* seg = keys + (size_t)chunk * 2048;
  seg[t] = sh[t];
  seg[t + 1024] = sh[t + 1024];
}

// merge two ascending 2048-arrays (A at base, B at base+span), keep lowest
// 2048 sorted ascending, write in place at A. span = 2048<<round.
__global__ __launch_bounds__(1024) void merge_top(uint64_t* __restrict__ keys,
                                                  int nmerge, int span) {
  __shared__ uint64_t sh[4096];
  int bid = blockIdx.x;
  int b = bid / nmerge;
  int m = bid - b * nmerge;
  uint64_t* A = keys + ((size_t)b << 15) + (size_t)m * (2 * span);
  const uint64_t* Bp = A + span;
  int t = threadIdx.x;
  // A ascending into [0,2048); B reversed into [2048,4096) -> bitonic
  sh[t] = A[t];
  sh[t + 1024] = A[t + 1024];
  sh[4095 - t] = Bp[t];
  sh[3071 - t] = Bp[t + 1024];
  __syncthreads();
  // half-cleaner stride 2048: lower half <- elementwise min (2048 smallest, bitonic)
  {
    uint64_t x0 = sh[t], y0 = sh[t + 2048];
    if (y0 < x0) sh[t] = y0;
    uint64_t x1 = sh[t + 1024], y1 = sh[t + 3072];
    if (y1 < x1) sh[t + 1024] = y1;
  }
  __syncthreads();
  // bitonic merge of lower 2048, ascending
  for (int j = 1024; j >= 1; j >>= 1) {
    int i = ((t & ~(j - 1)) << 1) | (t & (j - 1));
    int p = i | j;
    uint64_t x = sh[i], y = sh[p];
    if (x > y) { sh[i] = y; sh[p] = x; }
    __syncthreads();
  }
  A[t] = sh[t];
  A[t + 1024] = sh[t + 1024];
}

// ---------------- kernel: decode top-2000 proposals ----------------
__global__ void props_kernel(const uint64_t* __restrict__ keys, const float* __restrict__ scores,
                             const float* __restrict__ bb16, const float* __restrict__ bb12,
                             const float* __restrict__ bb8,  const float* __restrict__ bb4,
                             const float* __restrict__ im_info,
                             float* __restrict__ props, float* __restrict__ area,
                             float* __restrict__ tsc, int* __restrict__ tse) {
  int t = blockIdx.x * blockDim.x + threadIdx.x;
  if (t >= BB * PRE) return;
  int b = t / PRE;
  int r = t - b * PRE;
  int idx = (int)(keys[((size_t)b << 15) + r] & 0xffffffffu);
  int s, j, h, w, a;
  decode_idx(idx, s, j, h, w, a);
  const float* bp; int T, td, C;
  if (s == 0)      { bp = bb16; T = 1;  td = 16; C = AA*16*4; }
  else if (s == 1) { bp = bb12; T = 5;  td = 12; C = AA*12*4; }
  else if (s == 2) { bp = bb8;  T = 9;  td = 8;  C = AA*8*4;  }
  else             { bp = bb4;  T = 13; td = 4;  C = AA*4*4;  }

  float imh = im_info[b * 3 + 0] - 1.0f;
  float imw = im_info[b * 3 + 1] - 1.0f;

  float ax1 = BASE_ANC[a][0] + (float)(w * 16);
  float ay1 = BASE_ANC[a][1] + (float)(h * 16);
  float ax2 = BASE_ANC[a][2] + (float)(w * 16);
  float ay2 = BASE_ANC[a][3] + (float)(h * 16);
  float wa = ax2 - ax1 + 1.0f;
  float ha = ay2 - ay1 + 1.0f;
  float cx = ax1 + 0.5f * wa;
  float cy = ay1 + 0.5f * ha;

  int chanStride = T * HH * WW;
  float* pr = props + ((size_t)b * PRE + r) * (SS * 4);
  float acc = 0.0f;
  for (int f = 0; f < SS; ++f) {
    float x1, y1, x2, y2;
    if (f >= j && f < j + td) {
      int tt = f - j;
      int cb = (a * td + tt) * 4;
      size_t base = ((((size_t)b * C + cb) * T + j) * HH + h) * WW + w;
      float d0 = bp[base];
      float d1 = bp[base + chanStride];
      float d2 = bp[base + 2 * chanStride];
      float d3 = bp[base + 3 * chanStride];
      float pcx = d0 * wa + cx;
      float pcy = d1 * ha + cy;
      float pw = expf(d2) * wa;
      float ph = expf(d3) * ha;
      x1 = pcx - 0.5f * pw;
      y1 = pcy - 0.5f * ph;
      x2 = pcx + 0.5f * pw;
      y2 = pcy + 0.5f * ph;
    } else {
      x1 = 0.0f; y1 = 0.0f; x2 = 1.0f; y2 = 1.0f;
    }
    x1 = fminf(fmaxf(x1, 0.0f), imw);
    x2 = fminf(fmaxf(x2, 0.0f), imw);
    y1 = fminf(fmaxf(y1, 0.0f), imh);
    y2 = fminf(fmaxf(y2, 0.0f), imh);
    pr[f * 4 + 0] = x1;
    pr[f * 4 + 1] = y1;
    pr[f * 4 + 2] = x2;
    pr[f * 4 + 3] = y2;
    acc += (x2 - x1 + 1.0f) * (y2 - y1 + 1.0f);
  }
  area[b * PRE + r] = acc;
  tsc[b * PRE + r] = scores[b * NN + idx];
  tse[b * PRE + r] = j | ((j + td) << 8);   // temporal extent [si, ei)
}

// ---------------- kernel: suppression bitmask (pair-ILP quad skip) ------------
// r22 plateau diagnosis: latency-bound at 2 waves/SIMD (VALUBusy 50%, HBM
// 0.9% of peak). Occupancy can't rise (allocator pins 208 VGPR, 3 attempts).
// Remaining lever = ILP: TWO i-rows per iteration. B-set + dj shared between
// rows; the two FR chains are independent -> interleave and fill each other's
// stalls; quad branches merged per pair (scalar branch count per row halved).
// Bit-exact: out-of-range frames' stored props are exactly [0,0,1,1], so FR
// on them == dj (same op order); accumulation stays f=0..15 per row. Odd tail:
// row1 clamped to row0, second store guarded.
#define MITILE 128
#define MJC    8      // j-chunks of 256 (covers 2048 >= PRE)
#define MNIT   16     // i-tiles of 128 (16*128 = 2048 >= PRE)

#define FRA(r, Bf) { \
    float xx1 = fmaxf(r.x, Bf.x); float yy1 = fmaxf(r.y, Bf.y); \
    float xx2 = fminf(r.z, Bf.z); float yy2 = fminf(r.w, Bf.w); \
    inter0 += fmaxf(xx2 - xx1 + 1.0f, 0.0f) * \
              fmaxf(yy2 - yy1 + 1.0f, 0.0f); }
#define FRB(r, Bf) { \
    float xx1 = fmaxf(r.x, Bf.x); float yy1 = fmaxf(r.y, Bf.y); \
    float xx2 = fminf(r.z, Bf.z); float yy2 = fminf(r.w, Bf.w); \
    inter1 += fmaxf(xx2 - xx1 + 1.0f, 0.0f) * \
              fmaxf(yy2 - yy1 + 1.0f, 0.0f); }

#define PQUAD(q, Ba, Bb, Bc, Bd, dja, djb, djc, djd) \
  if ((ei0 <= 4*(q) || si0 >= 4*(q)+4) && (ei1 <= 4*(q) || si1 >= 4*(q)+4)) { \
    inter0 += dja; inter0 += djb; inter0 += djc; inter0 += djd; \
    inter1 += dja; inter1 += djb; inter1 += djc; inter1 += djd; \
  } else { \
    float4 r0a = shp[ii][4*(q)+0], r0b = shp[ii][4*(q)+1]; \
    float4 r0c = shp[ii][4*(q)+2], r0d = shp[ii][4*(q)+3]; \
    float4 r1a = shp[iiq][4*(q)+0], r1b = shp[iiq][4*(q)+1]; \
    float4 r1c = shp[iiq][4*(q)+2], r1d = shp[iiq][4*(q)+3]; \
    FRA(r0a,Ba) FRB(r1a,Ba) FRA(r0b,Bb) FRB(r1b,Bb) \
    FRA(r0c,Bc) FRB(r1c,Bc) FRA(r0d,Bd) FRB(r1d,Bd) \
  }

// mirror of FR with r = [0,0,1,1] (identical op order -> identical values)
#define DJCALC(Bf) \
  (fmaxf(fminf(1.0f, Bf.z) - fmaxf(0.0f, Bf.x) + 1.0f, 0.0f) * \
   fmaxf(fminf(1.0f, Bf.w) - fmaxf(0.0f, Bf.y) + 1.0f, 0.0f))

#define KEEP4(v) asm volatile("" : "+v"(v.x), "+v"(v.y), "+v"(v.z), "+v"(v.w))
#define KEEP1(v) asm volatile("" : "+v"(v))

__global__ __launch_bounds__(256, 4) void mask_kernel(const float* __restrict__ props,
                                                      const float* __restrict__ area,
                                                      const int* __restrict__ tse,
                                                      uint64_t* __restrict__ mask) {
  __shared__ float4 shp[MITILE][16];
  __shared__ float sha[MITILE];
  __shared__ int   shse[MITILE];
  int b  = blockIdx.z;
  int it = blockIdx.y;
  int jc = blockIdx.x;
  int i0 = it * MITILE;
  if (jc * 256 + 255 <= i0) return;       // entire block below diagonal

  int tid = threadIdx.x;
  int wave = tid >> 6;
  int lane = tid & 63;

  // stage 128 i-rows (+areas +extents) into LDS, coalesced float4
  const float4* srcb = (const float4*)(props + (size_t)b * PRE * 64);
  for (int u = tid; u < MITILE * 16; u += 256) {
    int row = u >> 4, q = u & 15;
    int ri = i0 + row; if (ri >= PRE) ri = PRE - 1;
    shp[row][q] = srcb[(size_t)ri * 16 + q];
  }
  if (tid < MITILE) {
    int ri = i0 + tid; if (ri >= PRE) ri = PRE - 1;
    sha[tid] = area[b * PRE + ri];
    shse[tid] = tse[b * PRE + ri];
  }
  __syncthreads();

  int jw = jc * 4 + wave;                 // this wave's j-word
  int j  = jw * 64 + lane;
  bool jv = j < PRE;
  int rj = jv ? j : PRE - 1;
  const float4* pj = (const float4*)(props + ((size_t)b * PRE + rj) * 64);
  float4 B0  = pj[0],  B1  = pj[1],  B2  = pj[2],  B3  = pj[3];
  float4 B4  = pj[4],  B5  = pj[5],  B6  = pj[6],  B7  = pj[7];
  float4 B8  = pj[8],  B9  = pj[9],  B10 = pj[10], B11 = pj[11];
  float4 B12 = pj[12], B13 = pj[13], B14 = pj[14], B15 = pj[15];
  float aj = area[b * PRE + rj];
  KEEP4(B0);  KEEP4(B1);  KEEP4(B2);  KEEP4(B3);
  KEEP4(B4);  KEEP4(B5);  KEEP4(B6);  KEEP4(B7);
  KEEP4(B8);  KEEP4(B9);  KEEP4(B10); KEEP4(B11);
  KEEP4(B12); KEEP4(B13); KEEP4(B14); KEEP4(B15);
  KEEP1(aj);

  // per-lane dummy-vs-j terms, one per frame (j fixed for the wave)
  float dj0  = DJCALC(B0),  dj1  = DJCALC(B1),  dj2  = DJCALC(B2),  dj3  = DJCALC(B3);
  float dj4  = DJCALC(B4),  dj5  = DJCALC(B5),  dj6  = DJCALC(B6),  dj7  = DJCALC(B7);
  float dj8  = DJCALC(B8),  dj9  = DJCALC(B9),  dj10 = DJCALC(B10), dj11 = DJCALC(B11);
  float dj12 = DJCALC(B12), dj13 = DJCALC(B13), dj14 = DJCALC(B14), dj15 = DJCALC(B15);

  int imax = PRE - i0; if (imax > MITILE) imax = MITILE;
  // per-wave diagonal cap: rows i >= jw*64+64 have no j>i bits in word jw
  int capw = jw * 64 + 64 - i0;
  if (imax > capw) imax = capw;
  if (imax <= 0) return;

  int ilast = imax - 1;
  // scalar state pipelined one pair ahead
  int se0_c = __builtin_amdgcn_readfirstlane(shse[0]);
  int se1_c = __builtin_amdgcn_readfirstlane(shse[1 <= ilast ? 1 : ilast]);
  float ai0_c = sha[0];
  float ai1_c = sha[1 <= ilast ? 1 : ilast];

  for (int ii = 0; ii < imax; ii += 2) {
    int n0 = ii + 2; if (n0 > ilast) n0 = ilast;
    int n1 = ii + 3; if (n1 > ilast) n1 = ilast;
    int se0_n = __builtin_amdgcn_readfirstlane(shse[n0]);
    int se1_n = __builtin_amdgcn_readfirstlane(shse[n1]);
    float ai0_n = sha[n0];
    float ai1_n = sha[n1];

    int iiq = ii + 1 <= ilast ? ii + 1 : ilast;   // row1 (clamped on odd tail)
    int si0 = se0_c & 255, ei0 = se0_c >> 8;
    int si1 = se1_c & 255, ei1 = se1_c >> 8;
    float inter0 = 0.0f, inter1 = 0.0f;

    PQUAD(0, B0,  B1,  B2,  B3,  dj0,  dj1,  dj2,  dj3)
    PQUAD(1, B4,  B5,  B6,  B7,  dj4,  dj5,  dj6,  dj7)
    PQUAD(2, B8,  B9,  B10, B11, dj8,  dj9,  dj10, dj11)
    PQUAD(3, B12, B13, B14, B15, dj12, dj13, dj14, dj15)

    int ir0 = i0 + ii;
    int ir1 = i0 + iiq;
    float iou0 = inter0 / (ai0_c + aj - inter0);
    float iou1 = inter1 / (ai1_c + aj - inter1);
    bool bit0 = jv && (j > ir0) && (iou0 > 0.7f);
    bool bit1 = jv && (j > ir1) && (iou1 > 0.7f);
    unsigned long long w0 = __ballot(bit0);
    unsigned long long w1 = __ballot(bit1);
    if (lane == 0) {
      mask[((size_t)b * PRE + ir0) * 32 + jw] = w0;
      if (ii + 1 < imax) mask[((size_t)b * PRE + ir1) * 32 + jw] = w1;
    }

    se0_c = se0_n; se1_c = se1_n;
    ai0_c = ai0_n; ai1_c = ai1_n;
  }
}

// ---------------- kernel: greedy NMS + kept list (20-deep prefetch pipeline) ----
#define GD 20    // prefetch depth; PRE % GD == 0
__global__ __launch_bounds__(64) void greedy_kernel(const uint64_t* __restrict__ mask,
                                                    int* __restrict__ kept,
                                                    int* __restrict__ nkeep) {
  int b = blockIdx.x;
  int lane = threadIdx.x;   // 64 lanes
  // 2000 bits: words 0..30 full, word 31 low 16 bits
  unsigned long long keep = 0ull;
  if (lane < 31) keep = ~0ull;
  else if (lane == 31) keep = 0xFFFFull;

  const uint64_t* m = mask + (size_t)b * PRE * 32;
  const bool ld = lane < 32;

  unsigned long long buf[GD];
  #pragma unroll
  for (int d = 0; d < GD; ++d)
    buf[d] = ld ? m[(size_t)d * 32 + lane] : 0ull;

  for (int i0 = 0; i0 < PRE; i0 += GD) {
    #pragma unroll
    for (int d = 0; d < GD; ++d) {
      int i = i0 + d;
      unsigned long long cur = buf[d];
      int ip = i + GD;
      buf[d] = (ld && ip < PRE) ? m[(size_t)ip * 32 + lane] : 0ull;
      // sanitize: only bits j > i are meaningful (sub-diagonal words may be unwritten)
      int iw = i >> 6;
      if (lane < iw) cur = 0ull;
      else if (lane == iw) cur &= ~((2ull << (i & 63)) - 1ull);
      unsigned long long kw = __shfl(keep, iw);
      if ((kw >> (i & 63)) & 1ull) {
        keep &= ~cur;
      }
    }
  }

  // build kept list (ascending indices), first 300
  int pc = __popcll(keep);
  int incl = pc;
  for (int o = 1; o < 32; o <<= 1) {
    int v = __shfl_up(incl, o);
    if (lane >= o) incl += v;
  }
  int excl = incl - pc;
  int total = __shfl(incl, 31);
  if (lane < 32) {
    int rank = excl;
    unsigned long long bits = keep;
    while (bits) {
      int bpos = __ffsll(bits) - 1;
      bits &= bits - 1ull;
      if (rank < POST) kept[b * POST + rank] = lane * 64 + bpos;
      rank++;
    }
  }
  if (lane == 0) nkeep[b] = total < POST ? total : POST;
}

// ---------------- kernel: write output ----------------
__global__ void out_kernel(const float* __restrict__ props, const float* __restrict__ tsc,
                           const int* __restrict__ kept, const int* __restrict__ nkeep,
                           float* __restrict__ out) {
  int t = blockIdx.x * blockDim.x + threadIdx.x;
  if (t >= BB * POST) return;
  int b = t / POST;
  int r = t - b * POST;
  float* row = out + (size_t)t * 66;
  row[0] = (float)b;
  if (r < nkeep[b]) {
    int i = kept[b * POST + r];
    const float* p = props + ((size_t)b * PRE + i) * 64;
    #pragma unroll
    for (int c = 0; c < 64; ++c) row[1 + c] = p[c];
    row[65] = tsc[b * PRE + i];
  } else {
    #pragma unroll
    for (int c = 1; c < 66; ++c) row[c] = 0.0f;
  }
}

// ---------------- launch ----------------
extern "C" void kernel_launch(void* const* d_in, const int* in_sizes, int n_in,
                              void* d_out, int out_size, void* d_ws, size_t ws_size,
                              hipStream_t stream) {
  const float* s16 = (const float*)d_in[0];
  const float* s12 = (const float*)d_in[1];
  const float* s8  = (const float*)d_in[2];
  const float* s4  = (const float*)d_in[3];
  const float* b16 = (const float*)d_in[4];
  const float* b12 = (const float*)d_in[5];
  const float* b8  = (const float*)d_in[6];
  const float* b4  = (const float*)d_in[7];
  const float* imi = (const float*)d_in[8];
  float* out = (float*)d_out;

  uint8_t* w = (uint8_t*)d_ws;
  uint64_t* keys = (uint64_t*)w;  w += (size_t)BB * NPAD * 8;        // 4,194,304
  float* scores  = (float*)w;     w += (size_t)BB * NN * 4;          // 1,053,696
  float* props   = (float*)w;     w += (size_t)BB * PRE * 64 * 4;    // 8,192,000
  float* area    = (float*)w;     w += (size_t)BB * PRE * 4;         //   128,000
  float* tsc     = (float*)w;     w += (size_t)BB * PRE * 4;         //   128,000
  int* tse       = (int*)w;       w += (size_t)BB * PRE * 4;         //   128,000
  uint64_t* mask = (uint64_t*)w;  w += (size_t)BB * PRE * 32 * 8;    // 8,192,000
  int* kept      = (int*)w;       w += (size_t)BB * POST * 4;        //    19,200
  int* nkeep     = (int*)w;       w += 64;

  // fused key-gen + chunk sort, then 4 tournament-merge rounds (in place)
  chunk_sort<<<BB * (NPAD / 2048), 1024, 0, stream>>>(s16, s12, s8, s4, keys, scores);
  merge_top<<<BB * 8, 1024, 0, stream>>>(keys, 8, 2048);
  merge_top<<<BB * 4, 1024, 0, stream>>>(keys, 4, 4096);
  merge_top<<<BB * 2, 1024, 0, stream>>>(keys, 2, 8192);
  merge_top<<<BB * 1, 1024, 0, stream>>>(keys, 1, 16384);

  props_kernel<<<(BB * PRE + 255) / 256, 256, 0, stream>>>(keys, scores, b16, b12, b8, b4,
                                                           imi, props, area, tsc, tse);
  {
    dim3 g(MJC, MNIT, BB);
    mask_kernel<<<g, 256, 0, stream>>>(props, area, tse, mask);
  }
  greedy_kernel<<<BB, 64, 0, stream>>>(mask, kept, nkeep);
  out_kernel<<<(BB * POST + 255) / 256, 256, 0, stream>>>(props, tsc, kept, nkeep, out);
}

// Round 25
// 637.550 us; speedup vs baseline: 1.1149x; 1.1149x over previous
//
#include <hip/hip_runtime.h>
#include <cstdint>
#include <cstddef>

// ---------------- problem constants ----------------
#define BB   16      // batch
#define HH   7
#define WW   7
#define AA   12
#define KAA  588     // H*W*A
#define NN   16464   // 28*KA tube proposals per batch
#define NPAD 32768   // padded segment per batch (16 chunks of 2048)
#define PRE  2000
#define POST 300
#define SS   16      // frames

// base anchors from generate_anchors(16), baked (exact halves, f32-exact)
__device__ __constant__ float BASE_ANC[12][4] = {
  {-15.f,  -4.f,  30.f,  19.f},
  {-38.f, -16.f,  53.f,  31.f},
  {-84.f, -40.f,  99.f,  55.f},
  {-176.f,-88.f, 191.f, 103.f},
  {-8.f,   -8.f,  23.f,  23.f},
  {-24.f, -24.f,  39.f,  39.f},
  {-56.f, -56.f,  71.f,  71.f},
  {-120.f,-120.f,135.f, 135.f},
  {-3.f,  -14.f,  18.f,  29.f},
  {-14.f, -36.f,  29.f,  51.f},
  {-36.f, -80.f,  51.f,  95.f},
  {-80.f, -168.f, 95.f, 183.f},
};

__device__ __forceinline__ void decode_idx(int idx, int& s, int& j, int& h, int& w, int& a) {
  int local;
  if (idx < 588)       { s = 0; local = idx; }
  else if (idx < 3528) { s = 1; local = idx - 588; }
  else if (idx < 8820) { s = 2; local = idx - 3528; }
  else                 { s = 3; local = idx - 8820; }
  j = local / KAA;
  int anc = local - j * KAA;
  h = anc / (WW * AA);
  int rem = anc - h * (WW * AA);
  w = rem / AA;
  a = rem - w * AA;
}

// ---------------- fused key-gen + per-chunk sort (top-2048 stage 1) ----------
__global__ __launch_bounds__(1024) void chunk_sort(const float* __restrict__ s16,
                                                   const float* __restrict__ s12,
                                                   const float* __restrict__ s8,
                                                   const float* __restrict__ s4,
                                                   uint64_t* __restrict__ keys,
                                                   float* __restrict__ scores) {
  __shared__ uint64_t sh[2048];
  int chunk = blockIdx.x;                 // 16 chunks per batch
  int b = chunk >> 4;
  int c = chunk & 15;
  int t = threadIdx.x;

  #pragma unroll
  for (int k = 0; k < 2; ++k) {
    int slot = c * 2048 + t + k * 1024;
    uint64_t key = ~0ull;
    if (slot < NN) {
      int s, j, h, w, a;
      decode_idx(slot, s, j, h, w, a);
      const float* sp; int T;
      if (s == 0)      { sp = s16; T = 1; }
      else if (s == 1) { sp = s12; T = 5; }
      else if (s == 2) { sp = s8;  T = 9; }
      else             { sp = s4;  T = 13; }
      float sc = sp[(((b * (2*AA) + AA + a) * T + j) * HH + h) * WW + w];
      scores[b * NN + slot] = sc;
      uint32_t u = __float_as_uint(sc);
      uint32_t mono = (u & 0x80000000u) ? ~u : (u | 0x80000000u);
      key = ((uint64_t)(~mono) << 32) | (uint32_t)slot;
    }
    sh[t + k * 1024] = key;
  }
  __syncthreads();

  for (int k = 2; k <= 2048; k <<= 1) {
    for (int j = k >> 1; j >= 1; j >>= 1) {
      int i = ((t & ~(j - 1)) << 1) | (t & (j - 1));
      int p = i | j;
      bool asc = ((i & k) == 0);          // standalone ascending sort
      uint64_t x = sh[i], y = sh[p];
      bool sw = asc ? (x > y) : (x < y);
      if (sw) { sh[i] = y; sh[p] = x; }
      __syncthreads();
    }
  }
  uint64_t* seg = keys + (size_t)chunk * 2048;
  seg[t] = sh[t];
  seg[t + 1024] = sh[t + 1024];
}

// merge two ascending 2048-arrays (A at base, B at base+span), keep lowest
// 2048 sorted ascending, write in place at A. span = 2048<<round.
__global__ __launch_bounds__(1024) void merge_top(uint64_t* __restrict__ keys,
                                                  int nmerge, int span) {
  __shared__ uint64_t sh[4096];
  int bid = blockIdx.x;
  int b = bid / nmerge;
  int m = bid - b * nmerge;
  uint64_t* A = keys + ((size_t)b << 15) + (size_t)m * (2 * span);
  const uint64_t* Bp = A + span;
  int t = threadIdx.x;
  // A ascending into [0,2048); B reversed into [2048,4096) -> bitonic
  sh[t] = A[t];
  sh[t + 1024] = A[t + 1024];
  sh[4095 - t] = Bp[t];
  sh[3071 - t] = Bp[t + 1024];
  __syncthreads();
  // half-cleaner stride 2048: lower half <- elementwise min (2048 smallest, bitonic)
  {
    uint64_t x0 = sh[t], y0 = sh[t + 2048];
    if (y0 < x0) sh[t] = y0;
    uint64_t x1 = sh[t + 1024], y1 = sh[t + 3072];
    if (y1 < x1) sh[t + 1024] = y1;
  }
  __syncthreads();
  // bitonic merge of lower 2048, ascending
  for (int j = 1024; j >= 1; j >>= 1) {
    int i = ((t & ~(j - 1)) << 1) | (t & (j - 1));
    int p = i | j;
    uint64_t x = sh[i], y = sh[p];
    if (x > y) { sh[i] = y; sh[p] = x; }
    __syncthreads();
  }
  A[t] = sh[t];
  A[t + 1024] = sh[t + 1024];
}

// ---------------- kernel: decode top-2000 proposals ----------------
__global__ void props_kernel(const uint64_t* __restrict__ keys, const float* __restrict__ scores,
                             const float* __restrict__ bb16, const float* __restrict__ bb12,
                             const float* __restrict__ bb8,  const float* __restrict__ bb4,
                             const float* __restrict__ im_info,
                             float* __restrict__ props, float* __restrict__ area,
                             float* __restrict__ tsc, int* __restrict__ tse) {
  int t = blockIdx.x * blockDim.x + threadIdx.x;
  if (t >= BB * PRE) return;
  int b = t / PRE;
  int r = t - b * PRE;
  int idx = (int)(keys[((size_t)b << 15) + r] & 0xffffffffu);
  int s, j, h, w, a;
  decode_idx(idx, s, j, h, w, a);
  const float* bp; int T, td, C;
  if (s == 0)      { bp = bb16; T = 1;  td = 16; C = AA*16*4; }
  else if (s == 1) { bp = bb12; T = 5;  td = 12; C = AA*12*4; }
  else if (s == 2) { bp = bb8;  T = 9;  td = 8;  C = AA*8*4;  }
  else             { bp = bb4;  T = 13; td = 4;  C = AA*4*4;  }

  float imh = im_info[b * 3 + 0] - 1.0f;
  float imw = im_info[b * 3 + 1] - 1.0f;

  float ax1 = BASE_ANC[a][0] + (float)(w * 16);
  float ay1 = BASE_ANC[a][1] + (float)(h * 16);
  float ax2 = BASE_ANC[a][2] + (float)(w * 16);
  float ay2 = BASE_ANC[a][3] + (float)(h * 16);
  float wa = ax2 - ax1 + 1.0f;
  float ha = ay2 - ay1 + 1.0f;
  float cx = ax1 + 0.5f * wa;
  float cy = ay1 + 0.5f * ha;

  int chanStride = T * HH * WW;
  float* pr = props + ((size_t)b * PRE + r) * (SS * 4);
  float acc = 0.0f;
  for (int f = 0; f < SS; ++f) {
    float x1, y1, x2, y2;
    if (f >= j && f < j + td) {
      int tt = f - j;
      int cb = (a * td + tt) * 4;
      size_t base = ((((size_t)b * C + cb) * T + j) * HH + h) * WW + w;
      float d0 = bp[base];
      float d1 = bp[base + chanStride];
      float d2 = bp[base + 2 * chanStride];
      float d3 = bp[base + 3 * chanStride];
      float pcx = d0 * wa + cx;
      float pcy = d1 * ha + cy;
      float pw = expf(d2) * wa;
      float ph = expf(d3) * ha;
      x1 = pcx - 0.5f * pw;
      y1 = pcy - 0.5f * ph;
      x2 = pcx + 0.5f * pw;
      y2 = pcy + 0.5f * ph;
    } else {
      x1 = 0.0f; y1 = 0.0f; x2 = 1.0f; y2 = 1.0f;
    }
    x1 = fminf(fmaxf(x1, 0.0f), imw);
    x2 = fminf(fmaxf(x2, 0.0f), imw);
    y1 = fminf(fmaxf(y1, 0.0f), imh);
    y2 = fminf(fmaxf(y2, 0.0f), imh);
    pr[f * 4 + 0] = x1;
    pr[f * 4 + 1] = y1;
    pr[f * 4 + 2] = x2;
    pr[f * 4 + 3] = y2;
    acc += (x2 - x1 + 1.0f) * (y2 - y1 + 1.0f);
  }
  area[b * PRE + r] = acc;
  tsc[b * PRE + r] = scores[b * NN + idx];
  tse[b * PRE + r] = j | ((j + td) << 8);   // temporal extent [si, ei)
}

// ---------------- kernel: suppression bitmask (2-way quad skip, r19-best) -----
// Measured best: 322us (r19/r20/r22). Failed alternatives (ledger): batched-
// plain 768, asm-pipelined 882, occupancy bounds ignored x2 / 530, scalar-pipe
// compile-fail + crash, 2-wave blocks 455 (HBM), pair-ILP 403 (VGPR spill:
// WRITE_SIZE 4.6->21.6MB). Allocator pins ~208 VGPR -> 2 waves/SIMD; this
// structure is the plateau. Restored exactly.
#define MITILE 128
#define MJC    8      // j-chunks of 256 (covers 2048 >= PRE)
#define MNIT   16     // i-tiles of 128 (16*128 = 2048 >= PRE)

#define FR(r, Bf) { \
    float xx1 = fmaxf(r.x, Bf.x); float yy1 = fmaxf(r.y, Bf.y); \
    float xx2 = fminf(r.z, Bf.z); float yy2 = fminf(r.w, Bf.w); \
    inter += fmaxf(xx2 - xx1 + 1.0f, 0.0f) * \
             fmaxf(yy2 - yy1 + 1.0f, 0.0f); }

#define QUAD(q, Ba, Bb, Bc, Bd, dja, djb, djc, djd) \
  if (ei <= 4*(q) || si >= 4*(q)+4) { \
    inter += dja; inter += djb; inter += djc; inter += djd; \
  } else { \
    float4 ra = shp[ii][4*(q)+0], rb = shp[ii][4*(q)+1]; \
    float4 rc = shp[ii][4*(q)+2], rd = shp[ii][4*(q)+3]; \
    FR(ra,Ba) FR(rb,Bb) FR(rc,Bc) FR(rd,Bd) \
  }

// mirror of FR with r = [0,0,1,1] (identical op order -> identical values)
#define DJCALC(Bf) \
  (fmaxf(fminf(1.0f, Bf.z) - fmaxf(0.0f, Bf.x) + 1.0f, 0.0f) * \
   fmaxf(fminf(1.0f, Bf.w) - fmaxf(0.0f, Bf.y) + 1.0f, 0.0f))

#define KEEP4(v) asm volatile("" : "+v"(v.x), "+v"(v.y), "+v"(v.z), "+v"(v.w))
#define KEEP1(v) asm volatile("" : "+v"(v))

__global__ __launch_bounds__(256, 4) void mask_kernel(const float* __restrict__ props,
                                                      const float* __restrict__ area,
                                                      const int* __restrict__ tse,
                                                      uint64_t* __restrict__ mask) {
  __shared__ float4 shp[MITILE][16];
  __shared__ float sha[MITILE];
  __shared__ int   shse[MITILE];
  int b  = blockIdx.z;
  int it = blockIdx.y;
  int jc = blockIdx.x;
  int i0 = it * MITILE;
  if (jc * 256 + 255 <= i0) return;       // entire block below diagonal

  int tid = threadIdx.x;
  int wave = tid >> 6;
  int lane = tid & 63;

  // stage 128 i-rows (+areas +extents) into LDS, coalesced float4
  const float4* srcb = (const float4*)(props + (size_t)b * PRE * 64);
  for (int u = tid; u < MITILE * 16; u += 256) {
    int row = u >> 4, q = u & 15;
    int ri = i0 + row; if (ri >= PRE) ri = PRE - 1;
    shp[row][q] = srcb[(size_t)ri * 16 + q];
  }
  if (tid < MITILE) {
    int ri = i0 + tid; if (ri >= PRE) ri = PRE - 1;
    sha[tid] = area[b * PRE + ri];
    shse[tid] = tse[b * PRE + ri];
  }
  __syncthreads();

  int jw = jc * 4 + wave;                 // this wave's j-word
  int j  = jw * 64 + lane;
  bool jv = j < PRE;
  int rj = jv ? j : PRE - 1;
  const float4* pj = (const float4*)(props + ((size_t)b * PRE + rj) * 64);
  float4 B0  = pj[0],  B1  = pj[1],  B2  = pj[2],  B3  = pj[3];
  float4 B4  = pj[4],  B5  = pj[5],  B6  = pj[6],  B7  = pj[7];
  float4 B8  = pj[8],  B9  = pj[9],  B10 = pj[10], B11 = pj[11];
  float4 B12 = pj[12], B13 = pj[13], B14 = pj[14], B15 = pj[15];
  float aj = area[b * PRE + rj];
  KEEP4(B0);  KEEP4(B1);  KEEP4(B2);  KEEP4(B3);
  KEEP4(B4);  KEEP4(B5);  KEEP4(B6);  KEEP4(B7);
  KEEP4(B8);  KEEP4(B9);  KEEP4(B10); KEEP4(B11);
  KEEP4(B12); KEEP4(B13); KEEP4(B14); KEEP4(B15);
  KEEP1(aj);

  // per-lane dummy-vs-j terms, one per frame (j fixed for the wave)
  float dj0  = DJCALC(B0),  dj1  = DJCALC(B1),  dj2  = DJCALC(B2),  dj3  = DJCALC(B3);
  float dj4  = DJCALC(B4),  dj5  = DJCALC(B5),  dj6  = DJCALC(B6),  dj7  = DJCALC(B7);
  float dj8  = DJCALC(B8),  dj9  = DJCALC(B9),  dj10 = DJCALC(B10), dj11 = DJCALC(B11);
  float dj12 = DJCALC(B12), dj13 = DJCALC(B13), dj14 = DJCALC(B14), dj15 = DJCALC(B15);

  int imax = PRE - i0; if (imax > MITILE) imax = MITILE;
  // per-wave diagonal cap: rows i >= jw*64+64 have no j>i bits in word jw
  int capw = jw * 64 + 64 - i0;
  if (imax > capw) imax = capw;
  if (imax <= 0) return;

  // scalar state pipelined one iteration ahead
  int se_c = __builtin_amdgcn_readfirstlane(shse[0]);
  float ai_c = sha[0];
  for (int ii = 0; ii < imax; ++ii) {
    int nn = ii + 1; if (nn >= imax) nn = imax - 1;
    int se_n = __builtin_amdgcn_readfirstlane(shse[nn]);
    float ai_n = sha[nn];

    int i = i0 + ii;
    int si = se_c & 255;
    int ei = se_c >> 8;
    float ai = ai_c;
    float inter = 0.0f;
    QUAD(0, B0,  B1,  B2,  B3,  dj0,  dj1,  dj2,  dj3)
    QUAD(1, B4,  B5,  B6,  B7,  dj4,  dj5,  dj6,  dj7)
    QUAD(2, B8,  B9,  B10, B11, dj8,  dj9,  dj10, dj11)
    QUAD(3, B12, B13, B14, B15, dj12, dj13, dj14, dj15)
    float iou = inter / (ai + aj - inter);
    bool bit = jv && (j > i) && (iou > 0.7f);
    unsigned long long word = __ballot(bit);
    if (lane == 0) mask[((size_t)b * PRE + i) * 32 + jw] = word;

    se_c = se_n;
    ai_c = ai_n;
  }
}

// ---------------- kernel: greedy NMS + kept list (20-deep prefetch pipeline) ----
#define GD 20    // prefetch depth; PRE % GD == 0
__global__ __launch_bounds__(64) void greedy_kernel(const uint64_t* __restrict__ mask,
                                                    int* __restrict__ kept,
                                                    int* __restrict__ nkeep) {
  int b = blockIdx.x;
  int lane = threadIdx.x;   // 64 lanes
  // 2000 bits: words 0..30 full, word 31 low 16 bits
  unsigned long long keep = 0ull;
  if (lane < 31) keep = ~0ull;
  else if (lane == 31) keep = 0xFFFFull;

  const uint64_t* m = mask + (size_t)b * PRE * 32;
  const bool ld = lane < 32;

  unsigned long long buf[GD];
  #pragma unroll
  for (int d = 0; d < GD; ++d)
    buf[d] = ld ? m[(size_t)d * 32 + lane] : 0ull;

  for (int i0 = 0; i0 < PRE; i0 += GD) {
    #pragma unroll
    for (int d = 0; d < GD; ++d) {
      int i = i0 + d;
      unsigned long long cur = buf[d];
      int ip = i + GD;
      buf[d] = (ld && ip < PRE) ? m[(size_t)ip * 32 + lane] : 0ull;
      // sanitize: only bits j > i are meaningful (sub-diagonal words may be unwritten)
      int iw = i >> 6;
      if (lane < iw) cur = 0ull;
      else if (lane == iw) cur &= ~((2ull << (i & 63)) - 1ull);
      unsigned long long kw = __shfl(keep, iw);
      if ((kw >> (i & 63)) & 1ull) {
        keep &= ~cur;
      }
    }
  }

  // build kept list (ascending indices), first 300
  int pc = __popcll(keep);
  int incl = pc;
  for (int o = 1; o < 32; o <<= 1) {
    int v = __shfl_up(incl, o);
    if (lane >= o) incl += v;
  }
  int excl = incl - pc;
  int total = __shfl(incl, 31);
  if (lane < 32) {
    int rank = excl;
    unsigned long long bits = keep;
    while (bits) {
      int bpos = __ffsll(bits) - 1;
      bits &= bits - 1ull;
      if (rank < POST) kept[b * POST + rank] = lane * 64 + bpos;
      rank++;
    }
  }
  if (lane == 0) nkeep[b] = total < POST ? total : POST;
}

// ---------------- kernel: write output ----------------
__global__ void out_kernel(const float* __restrict__ props, const float* __restrict__ tsc,
                           const int* __restrict__ kept, const int* __restrict__ nkeep,
                           float* __restrict__ out) {
  int t = blockIdx.x * blockDim.x + threadIdx.x;
  if (t >= BB * POST) return;
  int b = t / POST;
  int r = t - b * POST;
  float* row = out + (size_t)t * 66;
  row[0] = (float)b;
  if (r < nkeep[b]) {
    int i = kept[b * POST + r];
    const float* p = props + ((size_t)b * PRE + i) * 64;
    #pragma unroll
    for (int c = 0; c < 64; ++c) row[1 + c] = p[c];
    row[65] = tsc[b * PRE + i];
  } else {
    #pragma unroll
    for (int c = 1; c < 66; ++c) row[c] = 0.0f;
  }
}

// ---------------- launch ----------------
extern "C" void kernel_launch(void* const* d_in, const int* in_sizes, int n_in,
                              void* d_out, int out_size, void* d_ws, size_t ws_size,
                              hipStream_t stream) {
  const float* s16 = (const float*)d_in[0];
  const float* s12 = (const float*)d_in[1];
  const float* s8  = (const float*)d_in[2];
  const float* s4  = (const float*)d_in[3];
  const float* b16 = (const float*)d_in[4];
  const float* b12 = (const float*)d_in[5];
  const float* b8  = (const float*)d_in[6];
  const float* b4  = (const float*)d_in[7];
  const float* imi = (const float*)d_in[8];
  float* out = (float*)d_out;

  uint8_t* w = (uint8_t*)d_ws;
  uint64_t* keys = (uint64_t*)w;  w += (size_t)BB * NPAD * 8;        // 4,194,304
  float* scores  = (float*)w;     w += (size_t)BB * NN * 4;          // 1,053,696
  float* props   = (float*)w;     w += (size_t)BB * PRE * 64 * 4;    // 8,192,000
  float* area    = (float*)w;     w += (size_t)BB * PRE * 4;         //   128,000
  float* tsc     = (float*)w;     w += (size_t)BB * PRE * 4;         //   128,000
  int* tse       = (int*)w;       w += (size_t)BB * PRE * 4;         //   128,000
  uint64_t* mask = (uint64_t*)w;  w += (size_t)BB * PRE * 32 * 8;    // 8,192,000
  int* kept      = (int*)w;       w += (size_t)BB * POST * 4;        //    19,200
  int* nkeep     = (int*)w;       w += 64;

  // fused key-gen + chunk sort, then 4 tournament-merge rounds (in place)
  chunk_sort<<<BB * (NPAD / 2048), 1024, 0, stream>>>(s16, s12, s8, s4, keys, scores);
  merge_top<<<BB * 8, 1024, 0, stream>>>(keys, 8, 2048);
  merge_top<<<BB * 4, 1024, 0, stream>>>(keys, 4, 4096);
  merge_top<<<BB * 2, 1024, 0, stream>>>(keys, 2, 8192);
  merge_top<<<BB * 1, 1024, 0, stream>>>(keys, 1, 16384);

  props_kernel<<<(BB * PRE + 255) / 256, 256, 0, stream>>>(keys, scores, b16, b12, b8, b4,
                                                           imi, props, area, tsc, tse);
  {
    dim3 g(MJC, MNIT, BB);
    mask_kernel<<<g, 256, 0, stream>>>(props, area, tse, mask);
  }
  greedy_kernel<<<BB, 64, 0, stream>>>(mask, kept, nkeep);
  out_kernel<<<(BB * POST + 255) / 256, 256, 0, stream>>>(props, tsc, kept, nkeep, out);
}